// Round 16
// baseline (267.094 us; speedup 1.0000x reference)
//
#include <hip/hip_runtime.h>
#include <stdint.h>

// pairs_of_pairs: fused [concat -> conv1x1+relu x3]
// B=32, C=64, S=64, CC=128, OC=256. 2016 rows of 64 positions.
// R15: 768-thread blocks (12 waves = 3 waves/SIMD, +50% TLP vs all prior
// rounds), 3 rows/block, LDS 96KB = 3 x 32KB row-regions. Session model:
// per-row cost = per-layer fixed costs (barriers, W-streams) / rows-per-block,
// with waves/CU as latency cover; co-residency is unreachable (reg buckets),
// so scale the single block instead. Wave group g=wv>>2 owns row g; wave =
// 64o x 64pos, acc[4][4]=64 AGPR, 4A+4B : 16 MFMA per kk (0.625 loads/MFMA,
// = R11's efficiency). launch_bounds(768,1) -> ~170 reg cap, est ~130 used.
// Build: direct global->swizzled ds_write_b128, 1 barrier (R10). Epilogue:
// direct 64B-segment stores (R13 pattern; its spill was staging regs).
// Row region: X chunks [64pos][64ch] at 0/8/16KB (rolled chunk aliased from
// chunk2 at shifted pos, R12-proven); h overwrites region as [64pos][256ch].

typedef __attribute__((ext_vector_type(8))) __bf16 bf16x8;
typedef __attribute__((ext_vector_type(4))) float f32x4;
typedef __attribute__((ext_vector_type(4))) unsigned short u16x4;
typedef __attribute__((ext_vector_type(8))) unsigned short u16x8;

__device__ __forceinline__ unsigned short f2bf(float f) {
  unsigned int u = __builtin_bit_cast(unsigned int, f);
  u += 0x7FFFu + ((u >> 16) & 1u);
  return (unsigned short)(u >> 16);
}

// within a 32KB row-region: chunk ck at ck*4096 elems, [64 pos][64 ch]
// swizzled: 16B-slot = p*8 + ((c6>>3)^p)&7 -> ~2-way max.
__device__ __forceinline__ int xa(int ck, int p, int c6) {
  return ck * 4096 + (p * 8 + (((c6 >> 3) ^ p) & 7)) * 8 + (c6 & 7);
}
// h layout (layers 1-2 input): [64 pos][256 ch]: 16B-slot = p*32 + ((c>>3)^p)&31.
__device__ __forceinline__ int xh(int p, int c) {
  return (p * 32 + (((c >> 3) ^ p) & 31)) * 8 + (c & 7);
}

__global__ void wconv_kernel(const float* __restrict__ W1, const float* __restrict__ W2,
                             const float* __restrict__ W3, unsigned short* __restrict__ wb) {
  int i = (blockIdx.x * 256 + threadIdx.x) * 4;  // grid 64 -> 65536 per layer
  const float* Ws[3] = {W1, W2, W3};
#pragma unroll
  for (int L = 0; L < 3; ++L) {
    f32x4 a = *(const f32x4*)(Ws[L] + i);
    u16x4 p;
#pragma unroll
    for (int v = 0; v < 4; ++v) p[v] = f2bf(a[v]);
    *(u16x4*)(wb + L * 65536 + i) = p;
  }
}

__global__ __launch_bounds__(768, 1)
void fused_kernel(const float* __restrict__ x, const float* __restrict__ xc,
                  const unsigned short* __restrict__ wb,
                  const float* __restrict__ b1, const float* __restrict__ b2,
                  const float* __restrict__ b3, float* __restrict__ out) {
  __shared__ __align__(16) unsigned char lraw[98304];   // 3 x 32KB row-regions

  const int tid = threadIdx.x;    // 0..767
  const int lane = tid & 63;
  const int g16 = lane >> 4;
  const int l16 = lane & 15;
  const int wv = tid >> 6;        // wave 0..11
  const int grp = wv >> 2;        // row group 0..2
  const int ow = (wv & 3) * 64;   // o-range within group: [ow, ow+64)

  // the 3 row-units of this block
  const int u3 = blockIdx.x * 3;
  int ub[3], ud[3];
#pragma unroll
  for (int rr = 0; rr < 3; ++rr) {
    ub[rr] = (u3 + rr) / 63;
    ud[rr] = (u3 + rr) % 63;
  }

  // ---------------- build: direct global -> swizzled LDS, 1 barrier --------
  // 768 thr x 6 iters cover 3 rows x 3 chunks x 8 c-octets (72 octet-cols).
  {
    const int p = tid & 63;
    const int oc = tid >> 6;           // 0..11
#pragma unroll
    for (int t = 0; t < 6; ++t) {
      int g = t * 12 + oc;             // 0..71
      int rr = g / 24;
      int q = g - rr * 24;
      int ck = q >> 3;
      int c0 = (q & 7) << 3;
      int b = ub[rr], dd = ud[rr];
      u16x8 v;
#pragma unroll
      for (int j = 0; j < 8; ++j) {
        float f = (ck < 2) ? xc[(((b * 128 + ck * 64 + c0 + j) * 63) + dd) * 64 + p]
                           : x[(b * 64 + c0 + j) * 64 + p];
        v[j] = f2bf(f);
      }
      *(u16x8*)(((unsigned short*)lraw) + rr * 16384 + xa(ck, p, c0)) = v;
    }
  }
  __syncthreads();

  // ---------------- 3 fused conv1x1+relu layers (group works its row) ------
  unsigned short* Xg = ((unsigned short*)lraw) + grp * 16384;
  const int b = ub[grp];
  const int dd = ud[grp];
  const int d = dd + 1;

#pragma unroll 1
  for (int layer = 0; layer < 3; ++layer) {
    const unsigned short* wl = wb + layer * 65536;
    const float* bias = (layer == 0) ? b1 : (layer == 1) ? b2 : b3;

    f32x4 acc[4][4] = {};              // [mf][nf], wave tile = 64 o x 64 pos

#pragma unroll
    for (int kk = 0; kk < 8; ++kk) {
      int kb = kk * 32 + g16 * 8;      // lane-group's 8-wide k-base
      bf16x8 afr[4];
#pragma unroll
      for (int mf = 0; mf < 4; ++mf)
        afr[mf] = __builtin_bit_cast(
            bf16x8, *(const u16x8*)(wl + (ow + mf * 16 + l16) * 256 + kb));
      bf16x8 bfr[4];
#pragma unroll
      for (int nf = 0; nf < 4; ++nf) {
        int pp = nf * 16 + l16;        // position
        int addr;
        if (layer > 0)    addr = xh(pp, kb);
        else if (kk < 2)  addr = xa(0, pp, kb);
        else if (kk < 4)  addr = xa(1, pp, kb - 64);
        else if (kk < 6)  addr = xa(2, pp, kb - 128);
        else              addr = xa(2, (pp - d) & 63, kb - 192);  // rolled x
        bfr[nf] = __builtin_bit_cast(bf16x8, *(const u16x8*)&Xg[addr]);
      }
#pragma unroll
      for (int mf = 0; mf < 4; ++mf)
#pragma unroll
        for (int nf = 0; nf < 4; ++nf)
          acc[mf][nf] = __builtin_amdgcn_mfma_f32_16x16x32_bf16(afr[mf], bfr[nf], acc[mf][nf], 0, 0, 0);
    }

    if (layer < 2) {
      __syncthreads();  // all waves done reading their region this phase
      // bias + relu -> bf16 h into Xg (D frag: pos=l16 col, o=g16*4+v row)
#pragma unroll
      for (int mf = 0; mf < 4; ++mf) {
        int o0 = ow + mf * 16 + g16 * 4;
        f32x4 bv = *(const f32x4*)(bias + o0);
#pragma unroll
        for (int nf = 0; nf < 4; ++nf) {
          int pos = nf * 16 + l16;
          u16x4 pk;
#pragma unroll
          for (int v = 0; v < 4; ++v)
            pk[v] = f2bf(fmaxf(acc[mf][nf][v] + bv[v], 0.f));
          *(u16x4*)&Xg[xh(pos, o0)] = pk;
        }
      }
      __syncthreads();
    } else {
      // layer 2: bias+relu -> direct global stores. For each (mf,nf,v):
      // 16 lanes (l16) write 16 consecutive pos at fixed o = 64B segments.
#pragma unroll
      for (int mf = 0; mf < 4; ++mf) {
        int o0 = ow + mf * 16 + g16 * 4;
        f32x4 bv = *(const f32x4*)(bias + o0);
#pragma unroll
        for (int nf = 0; nf < 4; ++nf) {
          int pos = nf * 16 + l16;
#pragma unroll
          for (int v = 0; v < 4; ++v)
            out[(((b * 256 + o0 + v) * 63) + dd) * 64 + pos] =
                fmaxf(acc[mf][nf][v] + bv[v], 0.f);
        }
      }
    }
  }
}

extern "C" void kernel_launch(void* const* d_in, const int* in_sizes, int n_in,
                              void* d_out, int out_size, void* d_ws, size_t ws_size,
                              hipStream_t stream) {
  const float* x  = (const float*)d_in[0];
  const float* xc = (const float*)d_in[1];
  const float* W1 = (const float*)d_in[2];
  const float* b1 = (const float*)d_in[3];
  const float* W2 = (const float*)d_in[4];
  const float* b2 = (const float*)d_in[5];
  const float* W3 = (const float*)d_in[6];
  const float* b3 = (const float*)d_in[7];
  float* out = (float*)d_out;
  unsigned short* wb = (unsigned short*)d_ws;  // 3 x 256 x 256 bf16 = 384 KB

  wconv_kernel<<<64, 256, 0, stream>>>(W1, W2, W3, wb);
  fused_kernel<<<672, 768, 0, stream>>>(x, xc, wb, b1, b2, b3, out);
}

// Round 17
// 155.408 us; speedup vs baseline: 1.7187x; 1.7187x over previous
//
#include <hip/hip_runtime.h>
#include <stdint.h>

// pairs_of_pairs: fused [concat -> conv1x1+relu x3]
// B=32, C=64, S=64, CC=128, OC=256. 2016 rows of 64 positions.
// R16 = R11's structure at 2x the TLP: ONE 1024-thread block (16 waves =
// 4 waves/SIMD) per 2-row unit, grid 1008.
// Occupancy law (fits all session rounds): waves/SIMD = floor(512 / total
// regs (VGPR+AGPR, unified)); a 1024-thr block needs 4/SIMD => total <= 128.
// Wave = 32o x 64pos (o-slice s=wv>>1, pos-half ph=wv&1): acc[2][4] = 32
// AGPR + ~70 VGPR ~= 105 <= 128 (R2 proved 96-reg/16-wave works; R2's loss
// vs R11 was its staged build + 17 barriers, fixed here).
// Kept from R11: 2-row X (64KB, 4 chunk regions [128pos][64ch] swizzled,
// rolled chunk aliased from chunk2 at shifted pos), direct global->LDS build
// (1 barrier), full kk unroll, direct 64B-segment stores, 2 A : 4 B : 8 MFMA
// per wave-kk (A 2x vs R11 from L2-resident wb - not HBM).

typedef __attribute__((ext_vector_type(8))) __bf16 bf16x8;
typedef __attribute__((ext_vector_type(4))) float f32x4;
typedef __attribute__((ext_vector_type(4))) unsigned short u16x4;
typedef __attribute__((ext_vector_type(8))) unsigned short u16x8;

__device__ __forceinline__ unsigned short f2bf(float f) {
  unsigned int u = __builtin_bit_cast(unsigned int, f);
  u += 0x7FFFu + ((u >> 16) & 1u);
  return (unsigned short)(u >> 16);
}

// X: 4 chunk regions of [128 pos][64 ch] bf16 (8192 elems each).
// Within chunk: 16B-slot = pos*8 + ((c6/8) ^ (pos&7)) -> max 2-way (free).
__device__ __forceinline__ int xaddr(int pos, int c) {
  int slot = (pos << 3) + ((((c & 63) >> 3) ^ pos) & 7);
  return ((c >> 6) << 13) + (slot << 3) + (c & 7);
}

__global__ void wconv_kernel(const float* __restrict__ W1, const float* __restrict__ W2,
                             const float* __restrict__ W3, unsigned short* __restrict__ wb) {
  int i = (blockIdx.x * 256 + threadIdx.x) * 4;  // grid 64 -> 65536 per layer
  const float* Ws[3] = {W1, W2, W3};
#pragma unroll
  for (int L = 0; L < 3; ++L) {
    f32x4 a = *(const f32x4*)(Ws[L] + i);
    u16x4 p;
#pragma unroll
    for (int v = 0; v < 4; ++v) p[v] = f2bf(a[v]);
    *(u16x4*)(wb + L * 65536 + i) = p;
  }
}

__global__ __launch_bounds__(1024, 1)
void fused_kernel(const float* __restrict__ x, const float* __restrict__ xc,
                  const unsigned short* __restrict__ wb,
                  const float* __restrict__ b1, const float* __restrict__ b2,
                  const float* __restrict__ b3, float* __restrict__ out) {
  __shared__ __align__(16) unsigned char lraw[65536];
  unsigned short* X = (unsigned short*)lraw;   // 64KB, 4 chunk regions

  const int r = blockIdx.x;       // 0..1007
  const int b0 = r / 63;          // 0..15 ; row1 uses b0+16
  const int dd = r % 63;
  const int d = dd + 1;
  const int tid = threadIdx.x;    // 0..1023
  const int lane = tid & 63;
  const int g16 = lane >> 4;
  const int l16 = lane & 15;
  const int wv = tid >> 6;        // wave 0..15
  const int s = wv >> 1;          // o-slice 0..7: o in [s*32, s*32+32)
  const int ph = wv & 1;          // pos-half: pos in [ph*64, ph*64+64)
  const int ow = s * 32;

  // ---------------- build: direct global -> swizzled LDS, 1 barrier --------
  // thread = (p = tid&63, oc = tid>>6 in 0..15); 3 iters cover the 48
  // octet-chunks (2 rows x 3 chunks x 8 c-octets). Per iter: 8 coalesced f32
  // loads (lanes = consecutive pos, 256B segments) -> 1 swizzled ds_write_b128.
  {
    const int p = tid & 63;
    const int oc = tid >> 6;          // 0..15
#pragma unroll
    for (int t = 0; t < 3; ++t) {
      int g = t * 16 + oc;            // 0..47
      int rr = g / 24;                // row 0/1
      int q = g - rr * 24;
      int ck = q >> 3;                // chunk 0..2
      int c0 = (q & 7) << 3;          // 0,8,...,56
      int b = b0 + 16 * rr;
      u16x8 v;
#pragma unroll
      for (int j = 0; j < 8; ++j) {
        float f = (ck < 2) ? xc[(((b * 128 + ck * 64 + c0 + j) * 63) + dd) * 64 + p]
                           : x[(b * 64 + c0 + j) * 64 + p];
        v[j] = f2bf(f);
      }
      *(u16x8*)&X[xaddr(rr * 64 + p, ck * 64 + c0)] = v;
    }
  }
  __syncthreads();

  // ---------------- 3 fused conv1x1+relu layers ----------------
#pragma unroll 1
  for (int layer = 0; layer < 3; ++layer) {
    const unsigned short* wl = wb + layer * 65536;
    const float* bias = (layer == 0) ? b1 : (layer == 1) ? b2 : b3;
    const bool al3 = (layer == 0);   // layer-0 k>=192 aliases chunk2 shifted

    f32x4 acc[2][4] = {};            // [mf][nf], wave tile = 32 o x 64 pos

#pragma unroll
    for (int kk = 0; kk < 8; ++kk) { // FULL unroll
      int kb = kk * 32 + g16 * 8;    // lane-group's 8-wide k-base
      bool a3 = al3 && (kk >= 6);
      int cc = a3 ? (128 + (kb & 63)) : kb;  // rolled -> chunk2 region
      bf16x8 afr[2];
#pragma unroll
      for (int mf = 0; mf < 2; ++mf)
        afr[mf] = __builtin_bit_cast(
            bf16x8, *(const u16x8*)(wl + (ow + mf * 16 + l16) * 256 + kb));
      bf16x8 bfr[4];
#pragma unroll
      for (int nf = 0; nf < 4; ++nf) {
        int i = nf * 16 + l16;       // 0..63 within the pos-half
        int ie = ph * 64 + (a3 ? ((i - d) & 63) : i);
        bfr[nf] = __builtin_bit_cast(bf16x8, *(const u16x8*)&X[xaddr(ie, cc)]);
      }
#pragma unroll
      for (int mf = 0; mf < 2; ++mf)
#pragma unroll
        for (int nf = 0; nf < 4; ++nf)
          acc[mf][nf] = __builtin_amdgcn_mfma_f32_16x16x32_bf16(afr[mf], bfr[nf], acc[mf][nf], 0, 0, 0);
    }
    __syncthreads();  // all waves done reading X before overwrite

    if (layer < 2) {
      // bias + relu -> bf16 back into X (D frag: pos = l16 col, o = g16*4+v)
#pragma unroll
      for (int mf = 0; mf < 2; ++mf) {
        int o0 = ow + mf * 16 + g16 * 4;
        f32x4 bv = *(const f32x4*)(bias + o0);
#pragma unroll
        for (int nf = 0; nf < 4; ++nf) {
          int pos = ph * 64 + nf * 16 + l16;
          u16x4 pk;
#pragma unroll
          for (int v = 0; v < 4; ++v)
            pk[v] = f2bf(fmaxf(acc[mf][nf][v] + bv[v], 0.f));
          *(u16x4*)&X[xaddr(pos, o0)] = pk;
        }
      }
      __syncthreads();
    } else {
      // layer 2: bias+relu -> direct global stores. For each (mf,nf,v):
      // 16 lanes (l16) write 16 consecutive pos at fixed o = 64B segments.
      const int bq = b0 + 16 * ph;   // pos-half ph IS row ph
#pragma unroll
      for (int mf = 0; mf < 2; ++mf) {
        int o0 = ow + mf * 16 + g16 * 4;
        f32x4 bv = *(const f32x4*)(bias + o0);
#pragma unroll
        for (int nf = 0; nf < 4; ++nf) {
          int pos = nf * 16 + l16;   // within-row position
#pragma unroll
          for (int v = 0; v < 4; ++v)
            out[(((bq * 256 + o0 + v) * 63) + dd) * 64 + pos] =
                fmaxf(acc[mf][nf][v] + bv[v], 0.f);
        }
      }
    }
  }
}

extern "C" void kernel_launch(void* const* d_in, const int* in_sizes, int n_in,
                              void* d_out, int out_size, void* d_ws, size_t ws_size,
                              hipStream_t stream) {
  const float* x  = (const float*)d_in[0];
  const float* xc = (const float*)d_in[1];
  const float* W1 = (const float*)d_in[2];
  const float* b1 = (const float*)d_in[3];
  const float* W2 = (const float*)d_in[4];
  const float* b2 = (const float*)d_in[5];
  const float* W3 = (const float*)d_in[6];
  const float* b3 = (const float*)d_in[7];
  float* out = (float*)d_out;
  unsigned short* wb = (unsigned short*)d_ws;  // 3 x 256 x 256 bf16 = 384 KB

  wconv_kernel<<<64, 256, 0, stream>>>(W1, W2, W3, wb);
  fused_kernel<<<1008, 1024, 0, stream>>>(x, xc, wb, b1, b2, b3, out);
}

// Round 18
// 99.631 us; speedup vs baseline: 2.6808x; 1.5598x over previous
//
#include <hip/hip_runtime.h>
#include <stdint.h>

// pairs_of_pairs: fused [concat -> conv1x1+relu x3]
// B=32, C=64, S=64, CC=128, OC=256. 2016 rows of 64 positions.
// R17 = R11 (session best, 106.1us total) + DIRECT-STORE epilogue (no bounce).
// Decisive session data: TLP is NOT the limiter (R2/R16: 42-43% occ, slower;
// R11: 21% occ, fastest). Positive levers were per-wave efficiency and
// rows/block. R11 kept; its only remaining redundant phase was the epilogue
// LDS bounce (64KB RT + 3-4 barriers). Direct 64B-segment stores measured
// clean in R14 (WRITE 131.5MB). After layer-2's kk there is now ZERO
// synchronization - block stores from acc and exits (stores drain under the
// next block's build). Barriers/block ~10 -> 6.
// Structure: 2 rows/block (b0,b0+16), grid 1008, 512 thr, 8 waves x
// 32o x 128pos, acc[2][8]=64 AGPR, 2 A-loads : 16 MFMA per kk, X = 64KB
// 4-chunk swizzled (rolled chunk aliased from chunk2 at shifted pos),
// direct build with x-chunk overlap into layer-0 kk0-3, launch_bounds(512,1).

typedef __attribute__((ext_vector_type(8))) __bf16 bf16x8;
typedef __attribute__((ext_vector_type(4))) float f32x4;
typedef __attribute__((ext_vector_type(4))) unsigned short u16x4;
typedef __attribute__((ext_vector_type(8))) unsigned short u16x8;

__device__ __forceinline__ unsigned short f2bf(float f) {
  unsigned int u = __builtin_bit_cast(unsigned int, f);
  u += 0x7FFFu + ((u >> 16) & 1u);
  return (unsigned short)(u >> 16);
}

// X: 4 chunk regions of [128 pos][64 ch] bf16 (8192 elems each).
// Within chunk: 16B-slot = pos*8 + ((c6/8) ^ (pos&7)) -> max 2-way (free).
__device__ __forceinline__ int xaddr(int pos, int c) {
  int slot = (pos << 3) + ((((c & 63) >> 3) ^ pos) & 7);
  return ((c >> 6) << 13) + (slot << 3) + (c & 7);
}

__global__ void wconv_kernel(const float* __restrict__ W1, const float* __restrict__ W2,
                             const float* __restrict__ W3, unsigned short* __restrict__ wb) {
  int i = (blockIdx.x * 256 + threadIdx.x) * 4;  // grid 64 -> 65536 per layer
  const float* Ws[3] = {W1, W2, W3};
#pragma unroll
  for (int L = 0; L < 3; ++L) {
    f32x4 a = *(const f32x4*)(Ws[L] + i);
    u16x4 p;
#pragma unroll
    for (int v = 0; v < 4; ++v) p[v] = f2bf(a[v]);
    *(u16x4*)(wb + L * 65536 + i) = p;
  }
}

__global__ __launch_bounds__(512, 1)
void fused_kernel(const float* __restrict__ x, const float* __restrict__ xc,
                  const unsigned short* __restrict__ wb,
                  const float* __restrict__ b1, const float* __restrict__ b2,
                  const float* __restrict__ b3, float* __restrict__ out) {
  __shared__ __align__(16) unsigned char lraw[65536];
  unsigned short* X = (unsigned short*)lraw;   // 64KB, 4 chunk regions

  const int r = blockIdx.x;       // 0..1007
  const int b0 = r / 63;          // 0..15 ; row1 uses b0+16
  const int dd = r % 63;
  const int d = dd + 1;
  const int tid = threadIdx.x;    // 0..511
  const int lane = tid & 63;
  const int g16 = lane >> 4;
  const int l16 = lane & 15;
  const int wv = tid >> 6;        // wave 0..7

  const int p = tid & 63;         // build: position owned by this thread
  const int c0 = (tid >> 6) << 3; // build: c-octet 0,8,...,56

  // ---- issue x-chunk loads FIRST (latency hidden under build + kk0-3) ----
  float xreg[2][8];
#pragma unroll
  for (int rr = 0; rr < 2; ++rr)
#pragma unroll
    for (int j = 0; j < 8; ++j)
      xreg[rr][j] = x[((b0 + 16 * rr) * 64 + c0 + j) * 64 + p];

  // ---- build chunks 0,1 (xc) for both rows: direct global->LDS ----
#pragma unroll
  for (int cr = 0; cr < 4; ++cr) {
    const int rr = cr >> 1;
    const int ck = cr & 1;
    const int b = b0 + 16 * rr;
    u16x8 v;
#pragma unroll
    for (int j = 0; j < 8; ++j)
      v[j] = f2bf(xc[(((b * 128 + ck * 64 + c0 + j) * 63) + dd) * 64 + p]);
    *(u16x8*)&X[xaddr(rr * 64 + p, ck * 64 + c0)] = v;
  }
  __syncthreads();  // chunks 0,1 ready

  // ---------------- 3 fused conv1x1+relu layers ----------------
  for (int layer = 0; layer < 3; ++layer) {
    const unsigned short* wl = wb + layer * 65536;
    const float* bias = (layer == 0) ? b1 : (layer == 1) ? b2 : b3;
    const bool al3 = (layer == 0);     // layer 0: k in [192,256) aliases chunk2 shifted

    f32x4 acc[2][8] = {};              // [mf][nf], wave tile = 32 o x 128 pos
    const int ow = wv * 32;

#pragma unroll
    for (int kk = 0; kk < 8; ++kk) {   // FULL unroll; branches fold
      if (al3 && kk == 4) {
        // write x-chunk (c2) from regs, then barrier; kk0-3 used chunks 0,1 only
#pragma unroll
        for (int rr = 0; rr < 2; ++rr) {
          u16x8 v;
#pragma unroll
          for (int j = 0; j < 8; ++j) v[j] = f2bf(xreg[rr][j]);
          *(u16x8*)&X[xaddr(rr * 64 + p, 128 + c0)] = v;
        }
        __syncthreads();               // c2 ready for kk 4-7
      }
      int kb = kk * 32 + g16 * 8;      // this lane-group's k-base
      bool a3 = al3 && (kk >= 6);
      int cc = a3 ? (128 + (kb & 63)) : kb;  // rolled -> chunk2 region
      bf16x8 afr[2];
#pragma unroll
      for (int mf = 0; mf < 2; ++mf)
        afr[mf] = __builtin_bit_cast(
            bf16x8, *(const u16x8*)(wl + (ow + mf * 16 + l16) * 256 + kb));
      bf16x8 bfr[4];
#pragma unroll
      for (int nf = 0; nf < 4; ++nf) { // row0 positions 0..63
        int i = nf * 16 + l16;
        int ie = a3 ? ((i - d) & 63) : i;
        bfr[nf] = __builtin_bit_cast(bf16x8, *(const u16x8*)&X[xaddr(ie, cc)]);
      }
#pragma unroll
      for (int mf = 0; mf < 2; ++mf)
#pragma unroll
        for (int nf = 0; nf < 4; ++nf)
          acc[mf][nf] = __builtin_amdgcn_mfma_f32_16x16x32_bf16(afr[mf], bfr[nf], acc[mf][nf], 0, 0, 0);
#pragma unroll
      for (int nf = 0; nf < 4; ++nf) { // row1 positions 64..127
        int i = nf * 16 + l16;
        int ie = 64 + (a3 ? ((i - d) & 63) : i);
        bfr[nf] = __builtin_bit_cast(bf16x8, *(const u16x8*)&X[xaddr(ie, cc)]);
      }
#pragma unroll
      for (int mf = 0; mf < 2; ++mf)
#pragma unroll
        for (int nf = 0; nf < 4; ++nf)
          acc[mf][4 + nf] = __builtin_amdgcn_mfma_f32_16x16x32_bf16(afr[mf], bfr[nf], acc[mf][4 + nf], 0, 0, 0);
    }

    if (layer < 2) {
      __syncthreads();  // all waves done reading X before it is overwritten
      // bias + relu -> bf16 back into X (D frag: pos = l16 col, o = g16*4+v)
#pragma unroll
      for (int mf = 0; mf < 2; ++mf) {
        int o0 = ow + mf * 16 + g16 * 4;
        f32x4 bv = *(const f32x4*)(bias + o0);
#pragma unroll
        for (int nf = 0; nf < 8; ++nf) {
          int pos = nf * 16 + l16;     // 0..127 covers both rows
          u16x4 pk;
#pragma unroll
          for (int v = 0; v < 4; ++v)
            pk[v] = f2bf(fmaxf(acc[mf][nf][v] + bv[v], 0.f));
          *(u16x4*)&X[xaddr(pos, o0)] = pk;
        }
      }
      __syncthreads();
    } else {
      // layer 2: bias+relu -> DIRECT global stores, zero barriers.
      // For each (mf,nf,v): 16 lanes (l16) write 16 consecutive pos at fixed
      // o -> 64B segments (R14-validated: WRITE ~131MB, near-ideal sectors).
      // Stores drain while the next block's build begins on this CU.
#pragma unroll
      for (int rr = 0; rr < 2; ++rr) {
        const int bq = b0 + 16 * rr;
#pragma unroll
        for (int mf = 0; mf < 2; ++mf) {
          int o0 = ow + mf * 16 + g16 * 4;
          f32x4 bv = *(const f32x4*)(bias + o0);
#pragma unroll
          for (int nf = 0; nf < 4; ++nf) {
            int pos = nf * 16 + l16;   // within-row position
#pragma unroll
            for (int v = 0; v < 4; ++v)
              out[(((bq * 256 + o0 + v) * 63) + dd) * 64 + pos] =
                  fmaxf(acc[mf][rr * 4 + nf][v] + bv[v], 0.f);
          }
        }
      }
    }
  }
}

extern "C" void kernel_launch(void* const* d_in, const int* in_sizes, int n_in,
                              void* d_out, int out_size, void* d_ws, size_t ws_size,
                              hipStream_t stream) {
  const float* x  = (const float*)d_in[0];
  const float* xc = (const float*)d_in[1];
  const float* W1 = (const float*)d_in[2];
  const float* b1 = (const float*)d_in[3];
  const float* W2 = (const float*)d_in[4];
  const float* b2 = (const float*)d_in[5];
  const float* W3 = (const float*)d_in[6];
  const float* b3 = (const float*)d_in[7];
  float* out = (float*)d_out;
  unsigned short* wb = (unsigned short*)d_ws;  // 3 x 256 x 256 bf16 = 384 KB

  wconv_kernel<<<64, 256, 0, stream>>>(W1, W2, W3, wb);
  fused_kernel<<<1008, 512, 0, stream>>>(x, xc, wb, b1, b2, b3, out);
}